// Round 19
// baseline (352.757 us; speedup 1.0000x reference)
//
#include <hip/hip_runtime.h>

#define TOK  10560
#define CIMG 3072
#define KHD  1024

typedef unsigned short ushort_t;
typedef unsigned int u32;
using bf16x8 = __attribute__((ext_vector_type(8))) __bf16;
using f32x4  = __attribute__((ext_vector_type(4))) float;

#define GLD_LDS16(gp, lp) __builtin_amdgcn_global_load_lds( \
    (const __attribute__((address_space(1))) u32*)(gp), \
    (__attribute__((address_space(3))) u32*)(lp), 16, 0, 0)

static __device__ __forceinline__ unsigned short f2bf(float f){
  union { float f; unsigned u; } x; x.f = f;
  unsigned r = x.u + 0x7fffu + ((x.u >> 16) & 1u);
  return (unsigned short)(r >> 16);
}
static __device__ __forceinline__ float wave_sum(float v){
  #pragma unroll
  for (int off = 32; off > 0; off >>= 1) v += __shfl_xor(v, off, 64);
  return v;
}

// ---------------- conditioning MLP layer 1: h1 = silu(cp@w1+b1) --------------
__global__ __launch_bounds__(256) void k_pre1(const float* __restrict__ cond,
    const float* __restrict__ w1, const float* __restrict__ b1,
    float* __restrict__ h1){
  __shared__ float cs[16][16];
  int t = threadIdx.x;
  if (t < 256) cs[t >> 4][t & 15] = cond[(64 + (t >> 4)) * 16 + (t & 15)];
  __syncthreads();
  #pragma unroll
  for (int i = 0; i < 4; ++i){
    int idx = blockIdx.x * 256 + t + i * 2048;
    int r = idx >> 9, c = idx & 511;
    float s = b1[c];
    #pragma unroll
    for (int j = 0; j < 16; ++j) s += cs[r][j] * w1[j * 512 + c];
    h1[idx] = s / (1.f + __expf(-s));   // silu
  }
}

// ---------------- conditioning MLP layer 2: emb = h1@w2 + b2 -----------------
__global__ __launch_bounds__(256) void k_pre2(const float* __restrict__ h1,
    const float* __restrict__ w2, const float* __restrict__ b2,
    float* __restrict__ emb){
  int idx = blockIdx.x * 256 + threadIdx.x;
  int r = idx >> 9, c = idx & 511;
  const float* hp = h1 + r * 512;
  const float* wp = w2 + c;
  float acc = b2[c];
  #pragma unroll 8
  for (int j = 0; j < 512; ++j) acc += hp[j] * wp[(size_t)j * 512];
  emb[idx] = acc;
}

// ---------------- kv = mf @ kv_w, split-K partials (deterministic) ----------
__global__ __launch_bounds__(256) void k_kv(const float* __restrict__ emb,
                                            const float* __restrict__ kvw,
                                            float* __restrict__ part){
  int bl = blockIdx.x;                 // 3 l * 8 ntile * 16 kchunk = 384
  int l = bl / 128, rem = bl % 128, nt = rem / 16, kc = rem % 16;
  int n = nt * 256 + threadIdx.x;
  const float* e = emb + 2048 * l + kc * 256;   // mf[l][r] = emb[2048l + r]
  const float* w = kvw + (size_t)(kc * 256) * 2048 + n;
  float acc = 0.f;
  for (int r = 0; r < 256; ++r) acc += e[r] * w[(size_t)r * 2048];
  part[kc * 6144 + l * 2048 + n] = acc;
}

// ---------------- reduce partials, bias, k-RMSNorm ---------------------------
__global__ void k_knorm(const float* __restrict__ part, const float* __restrict__ kvb,
                        const float* __restrict__ knw, float* __restrict__ kn,
                        float* __restrict__ vv){
  int wid = threadIdx.x >> 6, lane = threadIdx.x & 63;
  for (int i = 0; i < 12; ++i){
    int g = wid * 12 + i;               // 0..47 = (l,h)
    int l = g >> 4, h = g & 15;
    int ik = l * 2048 + h * 64 + lane;
    float kk = kvb[h * 64 + lane];
    float v  = kvb[1024 + h * 64 + lane];
    for (int p = 0; p < 16; ++p){ kk += part[p * 6144 + ik]; v += part[p * 6144 + ik + 1024]; }
    float ss = wave_sum(kk * kk);
    kn[l * 1024 + h * 64 + lane] = kk * rsqrtf(ss * (1.f/64.f) + 1e-6f) * knw[lane];
    vv[l * 1024 + h * 64 + lane] = v;
  }
}

// ------- U[h*3+l][c] = sum_d v[l,h,d] * out_w[h*64+d][c]  (48 x 3072, f32) ---
__global__ __launch_bounds__(512) void k_uv(const float* __restrict__ vv,
    const float* __restrict__ ow, float* __restrict__ U){
  int b = blockIdx.x;             // 48 i * 6 cchunk = 288
  int i = b / 6, cc = b % 6;
  int h = i / 3, l = i % 3;
  int c = cc * 512 + threadIdx.x;
  const float* vp = vv + l * 1024 + h * 64;
  const float* wp = ow + (size_t)(h * 64) * 3072 + c;
  float acc = 0.f;
  #pragma unroll
  for (int d = 0; d < 64; ++d) acc += vp[d] * wp[(size_t)d * 3072];
  U[(size_t)i * 3072 + c] = acc;
}

// ------- base[c] = ob[c] + sum_h U[h*3][c];  D[h*2+l'][c] = U[h*3+1+l']-U[h*3]
__global__ __launch_bounds__(256) void k_ubase(const float* __restrict__ U,
    const float* __restrict__ ob, float* __restrict__ base, float* __restrict__ D){
  int c = blockIdx.x * 256 + threadIdx.x;   // 12 blocks
  float b = ob[c];
  #pragma unroll
  for (int h = 0; h < 16; ++h){
    float u0 = U[(size_t)(h * 3 + 0) * 3072 + c];
    float u1 = U[(size_t)(h * 3 + 1) * 3072 + c];
    float u2 = U[(size_t)(h * 3 + 2) * 3072 + c];
    b += u0;
    D[(size_t)(h * 2 + 0) * 3072 + c] = u1 - u0;
    D[(size_t)(h * 2 + 1) * 3072 + c] = u2 - u0;
  }
  base[c] = b;
}

// ---------------- transpose + f32->bf16 weight convert: dst[C][R] ------------
__global__ __launch_bounds__(256) void k_tconv(const float* __restrict__ src,
                                               ushort_t* __restrict__ dst,
                                               int R, int C){
  __shared__ float tile[32][33];
  int nTr = R >> 5;
  int tr = blockIdx.x % nTr, tc = blockIdx.x / nTr;
  int r0 = tr * 32, c0 = tc * 32, t = threadIdx.x;
  #pragma unroll
  for (int i = 0; i < 4; ++i){
    int idx = t + i * 256; int r = idx >> 5, c = idx & 31;
    tile[r][c] = src[(size_t)(r0 + r) * C + c0 + c];
  }
  __syncthreads();
  #pragma unroll
  for (int i = 0; i < 4; ++i){
    int idx = t + i * 256; int rr = idx >> 5, cc = idx & 31;
    dst[(size_t)(c0 + rr) * R + r0 + cc] = f2bf(tile[cc][rr]);
  }
}

// ---------------- x f32 -> bf16 streaming convert ----------------------------
__global__ __launch_bounds__(256) void k_xconv(const float* __restrict__ x,
                                               ushort_t* __restrict__ xb, int n4){
  for (int i = blockIdx.x * 256 + threadIdx.x; i < n4; i += gridDim.x * 256){
    float4 v = ((const float4*)x)[i];
    ushort4 o;
    o.x = f2bf(v.x); o.y = f2bf(v.y); o.z = f2bf(v.z); o.w = f2bf(v.w);
    ((ushort4*)xb)[i] = o;
  }
}

// ======== 192x128 bf16 MFMA Q-GEMM, BK=32, 4-deep ring, chunk-blocked LDS ====
// r18 ring/vmcnt skeleton (proven) + r16 chunk-blocked LDS layout (proven
// conflict-free): buffer 20KB = A[2 chunks][192 rows][32B] + B[2][128][32B]
// @ +12288. k-half within a 32B row swizzled by row bit2 (src-side pre-swizzle,
// read-side XOR). Stage counts unchanged (A:2, B:4) -> same vmcnt ledger:
//   steady: A vmcnt(4), B vmcnt(8); t==T-2: (2,4); t==T-1: (0,0).
// WAR: stage(t+3) targets buf[(t-1)&3], whose reads finished pre-barrier(t).
__global__ __launch_bounds__(512, 4) void gemm_fused(
    const ushort_t* __restrict__ A, const ushort_t* __restrict__ Bt,
    const float* __restrict__ bias, const float* __restrict__ kn,
    const float* __restrict__ qnw, float* __restrict__ acoef){
  __shared__ __align__(16) unsigned char lds[81920];
  const int tid = threadIdx.x;
  const int lane = tid & 63, wid = tid >> 6;
  const int wm = wid >> 1, wn = wid & 1;     // 4 x 2 waves -> per-wave 48x64
  const int l15 = lane & 15, kg = lane >> 4;

  // XCD swizzle: 440 = 8 * 55 -> bijective
  int bid = blockIdx.x;
  bid = (bid & 7) * 55 + (bid >> 3);
  const int mt = bid >> 3, nt = bid & 7;
  const int mbase = mt * 192, nbase = nt << 7;

  // staging: row = base + (lane>>1); 16B-half (lane&1) pre-swizzled by row bit2
  const int skh = ((lane & 1) ^ ((lane >> 3) & 1)) * 8;   // elem offset
  const ushort_t *gA0, *gA1, *gB00, *gB01, *gB10, *gB11;
  int dA0, dA1, dB00, dB01, dB10, dB11;
  if (wid < 6){
    const ushort_t* gr = A + (size_t)(mbase + wid * 32 + (lane >> 1)) * CIMG + skh;
    gA0 = gr;        gA1 = gr + 16;               // chunk 0 / chunk 1 (k+16)
    dA0 = wid * 1024;                dA1 = 6144 + wid * 1024;
    gB00 = gB01 = gB10 = gB11 = gr; dB00 = dB01 = dB10 = dB11 = dA0;
  } else {
    int v = wid - 6;
    const ushort_t* r0 = Bt + (size_t)(nbase + v * 64 + 0  + (lane >> 1)) * CIMG + skh;
    const ushort_t* r1 = Bt + (size_t)(nbase + v * 64 + 32 + (lane >> 1)) * CIMG + skh;
    gB00 = r0;       gB01 = r1;                   // chunk 0, row-groups 0/1
    gB10 = r0 + 16;  gB11 = r1 + 16;              // chunk 1
    dB00 = 12288 + v * 2048;         dB01 = dB00 + 1024;
    dB10 = 12288 + 4096 + v * 2048;  dB11 = dB10 + 1024;
    gA0 = gA1 = r0; dA0 = dA1 = dB00;
  }

  auto stage = [&](int t){
    const int gk = t * 32;
    const int bo = (t & 3) * 20480;
    if (wid < 6){
      GLD_LDS16(gA0 + gk, lds + bo + dA0);
      GLD_LDS16(gA1 + gk, lds + bo + dA1);
    } else {
      GLD_LDS16(gB00 + gk, lds + bo + dB00);
      GLD_LDS16(gB01 + gk, lds + bo + dB01);
      GLD_LDS16(gB10 + gk, lds + bo + dB10);
      GLD_LDS16(gB11 + gk, lds + bo + dB11);
    }
  };

  // fragment read bases: chunk (kg>>1), 32B rows, k-half (kg&1)^(row bit2)
  const int kh = ((kg & 1) ^ ((l15 >> 2) & 1)) * 16;
  const unsigned aBase = (unsigned)((kg >> 1) * 6144 + (wm * 48 + l15) * 32 + kh);
  const unsigned bBase = (unsigned)(12288 + (kg >> 1) * 4096 + (wn * 64 + l15) * 32 + kh);

  f32x4 acc[3][4];
  #pragma unroll
  for (int m = 0; m < 3; ++m)
    #pragma unroll
    for (int n = 0; n < 4; ++n) acc[m][n] = {0.f, 0.f, 0.f, 0.f};

  bf16x8 afr[3], bfr[4];

  const int T = CIMG / 32;   // 96

  stage(0); stage(1); stage(2);

  for (int t = 0; t < T; ++t){
    if (t < T - 2){
      if (wid < 6) asm volatile("s_waitcnt vmcnt(4)" ::: "memory");
      else         asm volatile("s_waitcnt vmcnt(8)" ::: "memory");
    } else if (t == T - 2){
      if (wid < 6) asm volatile("s_waitcnt vmcnt(2)" ::: "memory");
      else         asm volatile("s_waitcnt vmcnt(4)" ::: "memory");
    } else {
      asm volatile("s_waitcnt vmcnt(0)" ::: "memory");
    }
    __builtin_amdgcn_s_barrier();
    asm volatile("" ::: "memory");
    if (t + 3 < T) stage(t + 3);
    const unsigned char* base = lds + (t & 3) * 20480;
    #pragma unroll
    for (int n = 0; n < 4; ++n)
      bfr[n] = *(const bf16x8*)(base + bBase + n * 512);
    #pragma unroll
    for (int m = 0; m < 3; ++m)
      afr[m] = *(const bf16x8*)(base + aBase + m * 512);
    __builtin_amdgcn_s_setprio(1);
    #pragma unroll
    for (int m = 0; m < 3; ++m)
      #pragma unroll
      for (int n = 0; n < 4; ++n)
        acc[m][n] = __builtin_amdgcn_mfma_f32_16x16x32_bf16(afr[m], bfr[n], acc[m][n], 0, 0, 0);
    __builtin_amdgcn_s_setprio(0);
  }

  // -------- fused attention epilogue (registers + 16-lane shfl only) --------
  const int hglob = nt * 2 + wn;            // global head, 0..15
  float qnwv[4], qbv[4], knv0[4], knv1[4], knv2[4];
  #pragma unroll
  for (int n = 0; n < 4; ++n){
    int d = n * 16 + l15;
    qnwv[n] = qnw[d];
    qbv[n]  = bias[nbase + wn * 64 + d];
    knv0[n] = kn[hglob * 64 + d];
    knv1[n] = kn[1024 + hglob * 64 + d];
    knv2[n] = kn[2048 + hglob * 64 + d];
  }
  #pragma unroll
  for (int m = 0; m < 3; ++m){
    #pragma unroll
    for (int j = 0; j < 4; ++j){
      float q[4], ssq = 0.f;
      #pragma unroll
      for (int n = 0; n < 4; ++n){ q[n] = acc[m][n][j] + qbv[n]; ssq += q[n] * q[n]; }
      #pragma unroll
      for (int off = 1; off < 16; off <<= 1) ssq += __shfl_xor(ssq, off, 64);
      float rs = rsqrtf(ssq * (1.f/64.f) + 1e-6f);
      float s0 = 0.f, s1 = 0.f, s2 = 0.f;
      #pragma unroll
      for (int n = 0; n < 4; ++n){
        float qn = q[n] * rs * qnwv[n];
        s0 += qn * knv0[n]; s1 += qn * knv1[n]; s2 += qn * knv2[n];
      }
      #pragma unroll
      for (int off = 1; off < 16; off <<= 1){
        s0 += __shfl_xor(s0, off, 64);
        s1 += __shfl_xor(s1, off, 64);
        s2 += __shfl_xor(s2, off, 64);
      }
      s0 *= 0.125f; s1 *= 0.125f; s2 *= 0.125f;
      float mx = fmaxf(s0, fmaxf(s1, s2));
      float e0 = __expf(s0 - mx), e1 = __expf(s1 - mx), e2 = __expf(s2 - mx);
      float inv = 1.f / (e0 + e1 + e2);
      int grow = mbase + wm * 48 + m * 16 + kg * 4 + j;
      if (l15 == 0){
        float2 a12 = {e1 * inv, e2 * inv};
        *(float2*)(acoef + (size_t)grow * 32 + hglob * 2) = a12;
      }
    }
  }
}

// ------- out = x + base + acoef @ D  (rank-32, float4 I/O, b128 LDS reads) ---
__global__ __launch_bounds__(256) void k_rank32v(const float* __restrict__ x,
    const float* __restrict__ acoef, const float* __restrict__ D,
    const float* __restrict__ base, float* __restrict__ out){
  __shared__ __align__(16) float as[8][32];
  const int tid = threadIdx.x;
  const int rb = blockIdx.x / 3, cc = blockIdx.x % 3;
  const int r0 = rb * 8;                     // 1320*8 = 10560 exact
  const int c  = cc * 1024 + tid * 4;

  // x prefetch: 8 rows, issued before the k-loop -> overlaps D/a reads + FMA
  f32x4 xv[8];
  #pragma unroll
  for (int r = 0; r < 8; ++r)
    xv[r] = *(const f32x4*)(x + (size_t)(r0 + r) * 3072 + c);

  if (tid < 256) ((float*)as)[tid] = acoef[(size_t)r0 * 32 + tid];
  __syncthreads();

  f32x4 accv[8];
  #pragma unroll
  for (int r = 0; r < 8; ++r) accv[r] = {0.f, 0.f, 0.f, 0.f};

  #pragma unroll
  for (int k4 = 0; k4 < 8; ++k4){
    f32x4 d0 = *(const f32x4*)(D + (size_t)(k4 * 4 + 0) * 3072 + c);
    f32x4 d1 = *(const f32x4*)(D + (size_t)(k4 * 4 + 1) * 3072 + c);
    f32x4 d2 = *(const f32x4*)(D + (size_t)(k4 * 4 + 2) * 3072 + c);
    f32x4 d3 = *(const f32x4*)(D + (size_t)(k4 * 4 + 3) * 3072 + c);
    #pragma unroll
    for (int r = 0; r < 8; ++r){
      f32x4 a4 = *(const f32x4*)(&as[r][k4 * 4]);   // one ds_read_b128
      accv[r][0] += a4[0]*d0[0] + a4[1]*d1[0] + a4[2]*d2[0] + a4[3]*d3[0];
      accv[r][1] += a4[0]*d0[1] + a4[1]*d1[1] + a4[2]*d2[1] + a4[3]*d3[1];
      accv[r][2] += a4[0]*d0[2] + a4[1]*d1[2] + a4[2]*d2[2] + a4[3]*d3[2];
      accv[r][3] += a4[0]*d0[3] + a4[1]*d1[3] + a4[2]*d2[3] + a4[3]*d3[3];
    }
  }

  f32x4 b4 = *(const f32x4*)(base + c);
  #pragma unroll
  for (int r = 0; r < 8; ++r){
    const size_t o = (size_t)(r0 + r) * 3072 + c;
    f32x4 ov;
    ov[0] = xv[r][0] + b4[0] + accv[r][0];
    ov[1] = xv[r][1] + b4[1] + accv[r][1];
    ov[2] = xv[r][2] + b4[2] + accv[r][2];
    ov[3] = xv[r][3] + b4[3] + accv[r][3];
    *(f32x4*)(out + o) = ov;
  }
}

extern "C" void kernel_launch(void* const* d_in, const int* in_sizes, int n_in,
                              void* d_out, int out_size, void* d_ws, size_t ws_size,
                              hipStream_t stream){
  const float* x    = (const float*)d_in[0];
  const float* cond = (const float*)d_in[1];
  const float* mew1 = (const float*)d_in[2];
  const float* meb1 = (const float*)d_in[3];
  const float* mew2 = (const float*)d_in[4];
  const float* meb2 = (const float*)d_in[5];
  const float* qw   = (const float*)d_in[6];
  const float* qb   = (const float*)d_in[7];
  const float* kvw  = (const float*)d_in[8];
  const float* kvb  = (const float*)d_in[9];
  const float* qnw  = (const float*)d_in[10];
  const float* knw  = (const float*)d_in[11];
  const float* ow   = (const float*)d_in[12];
  const float* ob   = (const float*)d_in[13];

  char* ws = (char*)d_ws;
  float*    emb    = (float*)(ws + 0);          // 16x512 f32
  float*    kvpart = (float*)(ws + 32768);      // 16x6144 f32
  float*    kn     = (float*)(ws + 425984);     // 3x1024 f32
  float*    vv     = (float*)(ws + 438272);     // 3x1024 f32
  ushort_t* qwt    = (ushort_t*)(ws + 450560);  // [1024][3072] bf16
  float*    U      = (float*)(ws + 6742016);    // [48][3072] f32
  float*    base   = (float*)(ws + 7331840);    // [3072] f32
  float*    Dbuf   = (float*)(ws + 7344128);    // [32][3072] f32
  float*    acoef  = (float*)(ws + 7737344);    // [10560][32] f32
  float*    h1buf  = (float*)(ws + 9089024);    // 16x512 f32

  // xb (bf16 x) lives in d_out: needed only until the Q-GEMM; k_rank32v
  // fully overwrites d_out at the end of every call.
  ushort_t* xb = (ushort_t*)d_out;

  k_pre1<<<8, 256, 0, stream>>>(cond, mew1, meb1, h1buf);
  k_pre2<<<32, 256, 0, stream>>>(h1buf, mew2, meb2, emb);
  k_kv<<<384, 256, 0, stream>>>(emb, kvw, kvpart);
  k_knorm<<<1, 256, 0, stream>>>(kvpart, kvb, knw, kn, vv);
  k_uv<<<288, 512, 0, stream>>>(vv, ow, U);
  k_ubase<<<12, 256, 0, stream>>>(U, ob, base, Dbuf);
  k_tconv<<<3072, 256, 0, stream>>>(qw, qwt, 3072, 1024);
  k_xconv<<<2048, 256, 0, stream>>>(x, xb, (TOK * CIMG) / 4);
  gemm_fused<<<440, 512, 0, stream>>>(xb, qwt, qb, kn, qnw, acoef);
  k_rank32v<<<3960, 256, 0, stream>>>(x, acoef, Dbuf, base, (float*)d_out);
}

// Round 20
// 264.430 us; speedup vs baseline: 1.3340x; 1.3340x over previous
//
#include <hip/hip_runtime.h>

#define TOK  10560
#define CIMG 3072
#define KHD  1024

typedef unsigned short ushort_t;
typedef unsigned int u32;
using bf16x8 = __attribute__((ext_vector_type(8))) __bf16;
using f32x4  = __attribute__((ext_vector_type(4))) float;

#define GLD_LDS16(gp, lp) __builtin_amdgcn_global_load_lds( \
    (const __attribute__((address_space(1))) u32*)(gp), \
    (__attribute__((address_space(3))) u32*)(lp), 16, 0, 0)

static __device__ __forceinline__ unsigned short f2bf(float f){
  union { float f; unsigned u; } x; x.f = f;
  unsigned r = x.u + 0x7fffu + ((x.u >> 16) & 1u);
  return (unsigned short)(r >> 16);
}
static __device__ __forceinline__ float wave_sum(float v){
  #pragma unroll
  for (int off = 32; off > 0; off >>= 1) v += __shfl_xor(v, off, 64);
  return v;
}

// ---------------- conditioning MLP layer 1: h1 = silu(cp@w1+b1) --------------
__global__ __launch_bounds__(256) void k_pre1(const float* __restrict__ cond,
    const float* __restrict__ w1, const float* __restrict__ b1,
    float* __restrict__ h1){
  __shared__ float cs[16][16];
  int t = threadIdx.x;
  if (t < 256) cs[t >> 4][t & 15] = cond[(64 + (t >> 4)) * 16 + (t & 15)];
  __syncthreads();
  #pragma unroll
  for (int i = 0; i < 4; ++i){
    int idx = blockIdx.x * 256 + t + i * 2048;
    int r = idx >> 9, c = idx & 511;
    float s = b1[c];
    #pragma unroll
    for (int j = 0; j < 16; ++j) s += cs[r][j] * w1[j * 512 + c];
    h1[idx] = s / (1.f + __expf(-s));   // silu
  }
}

// ---------------- conditioning MLP layer 2: emb = h1@w2 + b2 -----------------
__global__ __launch_bounds__(256) void k_pre2(const float* __restrict__ h1,
    const float* __restrict__ w2, const float* __restrict__ b2,
    float* __restrict__ emb){
  int idx = blockIdx.x * 256 + threadIdx.x;
  int r = idx >> 9, c = idx & 511;
  const float* hp = h1 + r * 512;
  const float* wp = w2 + c;
  float acc = b2[c];
  #pragma unroll 8
  for (int j = 0; j < 512; ++j) acc += hp[j] * wp[(size_t)j * 512];
  emb[idx] = acc;
}

// ---------------- kv = mf @ kv_w, split-K partials (deterministic) ----------
__global__ __launch_bounds__(256) void k_kv(const float* __restrict__ emb,
                                            const float* __restrict__ kvw,
                                            float* __restrict__ part){
  int bl = blockIdx.x;                 // 3 l * 8 ntile * 16 kchunk = 384
  int l = bl / 128, rem = bl % 128, nt = rem / 16, kc = rem % 16;
  int n = nt * 256 + threadIdx.x;
  const float* e = emb + 2048 * l + kc * 256;   // mf[l][r] = emb[2048l + r]
  const float* w = kvw + (size_t)(kc * 256) * 2048 + n;
  float acc = 0.f;
  for (int r = 0; r < 256; ++r) acc += e[r] * w[(size_t)r * 2048];
  part[kc * 6144 + l * 2048 + n] = acc;
}

// ---------------- reduce partials, bias, k-RMSNorm ---------------------------
__global__ void k_knorm(const float* __restrict__ part, const float* __restrict__ kvb,
                        const float* __restrict__ knw, float* __restrict__ kn,
                        float* __restrict__ vv){
  int wid = threadIdx.x >> 6, lane = threadIdx.x & 63;
  for (int i = 0; i < 12; ++i){
    int g = wid * 12 + i;               // 0..47 = (l,h)
    int l = g >> 4, h = g & 15;
    int ik = l * 2048 + h * 64 + lane;
    float kk = kvb[h * 64 + lane];
    float v  = kvb[1024 + h * 64 + lane];
    for (int p = 0; p < 16; ++p){ kk += part[p * 6144 + ik]; v += part[p * 6144 + ik + 1024]; }
    float ss = wave_sum(kk * kk);
    kn[l * 1024 + h * 64 + lane] = kk * rsqrtf(ss * (1.f/64.f) + 1e-6f) * knw[lane];
    vv[l * 1024 + h * 64 + lane] = v;
  }
}

// ------- U[h*3+l][c] = sum_d v[l,h,d] * out_w[h*64+d][c]  (48 x 3072, f32) ---
__global__ __launch_bounds__(512) void k_uv(const float* __restrict__ vv,
    const float* __restrict__ ow, float* __restrict__ U){
  int b = blockIdx.x;             // 48 i * 6 cchunk = 288
  int i = b / 6, cc = b % 6;
  int h = i / 3, l = i % 3;
  int c = cc * 512 + threadIdx.x;
  const float* vp = vv + l * 1024 + h * 64;
  const float* wp = ow + (size_t)(h * 64) * 3072 + c;
  float acc = 0.f;
  #pragma unroll
  for (int d = 0; d < 64; ++d) acc += vp[d] * wp[(size_t)d * 3072];
  U[(size_t)i * 3072 + c] = acc;
}

// ------- base[c] = ob[c] + sum_h U[h*3][c];  D[h*2+l'][c] = U[h*3+1+l']-U[h*3]
__global__ __launch_bounds__(256) void k_ubase(const float* __restrict__ U,
    const float* __restrict__ ob, float* __restrict__ base, float* __restrict__ D){
  int c = blockIdx.x * 256 + threadIdx.x;   // 12 blocks
  float b = ob[c];
  #pragma unroll
  for (int h = 0; h < 16; ++h){
    float u0 = U[(size_t)(h * 3 + 0) * 3072 + c];
    float u1 = U[(size_t)(h * 3 + 1) * 3072 + c];
    float u2 = U[(size_t)(h * 3 + 2) * 3072 + c];
    b += u0;
    D[(size_t)(h * 2 + 0) * 3072 + c] = u1 - u0;
    D[(size_t)(h * 2 + 1) * 3072 + c] = u2 - u0;
  }
  base[c] = b;
}

// ---------------- transpose + f32->bf16 weight convert: dst[C][R] ------------
__global__ __launch_bounds__(256) void k_tconv(const float* __restrict__ src,
                                               ushort_t* __restrict__ dst,
                                               int R, int C){
  __shared__ float tile[32][33];
  int nTr = R >> 5;
  int tr = blockIdx.x % nTr, tc = blockIdx.x / nTr;
  int r0 = tr * 32, c0 = tc * 32, t = threadIdx.x;
  #pragma unroll
  for (int i = 0; i < 4; ++i){
    int idx = t + i * 256; int r = idx >> 5, c = idx & 31;
    tile[r][c] = src[(size_t)(r0 + r) * C + c0 + c];
  }
  __syncthreads();
  #pragma unroll
  for (int i = 0; i < 4; ++i){
    int idx = t + i * 256; int rr = idx >> 5, cc = idx & 31;
    dst[(size_t)(c0 + rr) * R + r0 + cc] = f2bf(tile[cc][rr]);
  }
}

// ---------------- x f32 -> bf16 streaming convert ----------------------------
__global__ __launch_bounds__(256) void k_xconv(const float* __restrict__ x,
                                               ushort_t* __restrict__ xb, int n4){
  for (int i = blockIdx.x * 256 + threadIdx.x; i < n4; i += gridDim.x * 256){
    float4 v = ((const float4*)x)[i];
    ushort4 o;
    o.x = f2bf(v.x); o.y = f2bf(v.y); o.z = f2bf(v.z); o.w = f2bf(v.w);
    ((ushort4*)xb)[i] = o;
  }
}

// ======== 192x128 bf16 MFMA Q-GEMM, BK=32, 4-deep LDS ring, fused attn =======
// (round-18 version, byte-identical — verified 95us, total-best 260us)
__global__ __launch_bounds__(512, 4) void gemm_fused(
    const ushort_t* __restrict__ A, const ushort_t* __restrict__ Bt,
    const float* __restrict__ bias, const float* __restrict__ kn,
    const float* __restrict__ qnw, float* __restrict__ acoef){
  __shared__ __align__(16) unsigned char lds[81920];
  const int tid = threadIdx.x;
  const int lane = tid & 63, wid = tid >> 6;
  const int wm = wid >> 1, wn = wid & 1;     // 4 x 2 waves -> per-wave 48x64
  const int l15 = lane & 15, kg = lane >> 4;

  // XCD swizzle: 440 = 8 * 55 -> bijective
  int bid = blockIdx.x;
  bid = (bid & 7) * 55 + (bid >> 3);
  const int mt = bid >> 3, nt = bid & 7;
  const int mbase = mt * 192, nbase = nt << 7;

  // staging pointers (per thread): src chunk swizzled, dst linear 1KB slots
  const int skb = ((lane & 3) ^ ((lane >> 4) & 3)) * 8;   // elem offset
  const int lrow = lane >> 2;                             // 0..15 within slot
  const ushort_t *g0, *g1, *g2, *g3;
  int d0, d1, d2, d3;
  if (wid < 6){
    int r0 = (wid * 2 + 0) * 16 + lrow;
    int r1 = (wid * 2 + 1) * 16 + lrow;
    g0 = A + (size_t)(mbase + r0) * CIMG + skb;
    g1 = A + (size_t)(mbase + r1) * CIMG + skb;
    g2 = g0; g3 = g0;
    d0 = (wid * 2 + 0) * 1024;
    d1 = (wid * 2 + 1) * 1024;
    d2 = d0; d3 = d0;
  } else {
    int v = wid - 6;
    int r0 = (v * 4 + 0) * 16 + lrow, r1 = (v * 4 + 1) * 16 + lrow;
    int r2 = (v * 4 + 2) * 16 + lrow, r3 = (v * 4 + 3) * 16 + lrow;
    g0 = Bt + (size_t)(nbase + r0) * CIMG + skb;
    g1 = Bt + (size_t)(nbase + r1) * CIMG + skb;
    g2 = Bt + (size_t)(nbase + r2) * CIMG + skb;
    g3 = Bt + (size_t)(nbase + r3) * CIMG + skb;
    d0 = 12288 + (v * 4 + 0) * 1024;
    d1 = 12288 + (v * 4 + 1) * 1024;
    d2 = 12288 + (v * 4 + 2) * 1024;
    d3 = 12288 + (v * 4 + 3) * 1024;
  }

  auto stage = [&](int t){
    const int gk = t * 32;
    const int bo = (t & 3) * 20480;
    if (wid < 6){
      GLD_LDS16(g0 + gk, lds + bo + d0);
      GLD_LDS16(g1 + gk, lds + bo + d1);
    } else {
      GLD_LDS16(g0 + gk, lds + bo + d0);
      GLD_LDS16(g1 + gk, lds + bo + d1);
      GLD_LDS16(g2 + gk, lds + bo + d2);
      GLD_LDS16(g3 + gk, lds + bo + d3);
    }
  };

  // fragment read bases
  const int swz = (kg ^ ((l15 >> 2) & 3)) * 16;
  const unsigned aBase = (unsigned)((wm * 48 + l15) * 64 + swz);
  const unsigned bBase = (unsigned)(12288 + (wn * 64 + l15) * 64 + swz);

  f32x4 acc[3][4];
  #pragma unroll
  for (int m = 0; m < 3; ++m)
    #pragma unroll
    for (int n = 0; n < 4; ++n) acc[m][n] = {0.f, 0.f, 0.f, 0.f};

  bf16x8 afr[3], bfr[4];

  const int T = CIMG / 32;   // 96

  stage(0); stage(1); stage(2);

  for (int t = 0; t < T; ++t){
    if (t < T - 2){
      if (wid < 6) asm volatile("s_waitcnt vmcnt(4)" ::: "memory");
      else         asm volatile("s_waitcnt vmcnt(8)" ::: "memory");
    } else if (t == T - 2){
      if (wid < 6) asm volatile("s_waitcnt vmcnt(2)" ::: "memory");
      else         asm volatile("s_waitcnt vmcnt(4)" ::: "memory");
    } else {
      asm volatile("s_waitcnt vmcnt(0)" ::: "memory");
    }
    __builtin_amdgcn_s_barrier();
    asm volatile("" ::: "memory");
    if (t + 3 < T) stage(t + 3);
    const unsigned char* base = lds + (t & 3) * 20480;
    #pragma unroll
    for (int n = 0; n < 4; ++n)
      bfr[n] = *(const bf16x8*)(base + bBase + n * 1024);
    #pragma unroll
    for (int m = 0; m < 3; ++m)
      afr[m] = *(const bf16x8*)(base + aBase + m * 1024);
    __builtin_amdgcn_s_setprio(1);
    #pragma unroll
    for (int m = 0; m < 3; ++m)
      #pragma unroll
      for (int n = 0; n < 4; ++n)
        acc[m][n] = __builtin_amdgcn_mfma_f32_16x16x32_bf16(afr[m], bfr[n], acc[m][n], 0, 0, 0);
    __builtin_amdgcn_s_setprio(0);
  }

  // -------- fused attention epilogue (registers + 16-lane shfl only) --------
  const int hglob = nt * 2 + wn;            // global head, 0..15
  float qnwv[4], qbv[4], knv0[4], knv1[4], knv2[4];
  #pragma unroll
  for (int n = 0; n < 4; ++n){
    int d = n * 16 + l15;
    qnwv[n] = qnw[d];
    qbv[n]  = bias[nbase + wn * 64 + d];
    knv0[n] = kn[hglob * 64 + d];
    knv1[n] = kn[1024 + hglob * 64 + d];
    knv2[n] = kn[2048 + hglob * 64 + d];
  }
  #pragma unroll
  for (int m = 0; m < 3; ++m){
    #pragma unroll
    for (int j = 0; j < 4; ++j){
      float q[4], ssq = 0.f;
      #pragma unroll
      for (int n = 0; n < 4; ++n){ q[n] = acc[m][n][j] + qbv[n]; ssq += q[n] * q[n]; }
      #pragma unroll
      for (int off = 1; off < 16; off <<= 1) ssq += __shfl_xor(ssq, off, 64);
      float rs = rsqrtf(ssq * (1.f/64.f) + 1e-6f);
      float s0 = 0.f, s1 = 0.f, s2 = 0.f;
      #pragma unroll
      for (int n = 0; n < 4; ++n){
        float qn = q[n] * rs * qnwv[n];
        s0 += qn * knv0[n]; s1 += qn * knv1[n]; s2 += qn * knv2[n];
      }
      #pragma unroll
      for (int off = 1; off < 16; off <<= 1){
        s0 += __shfl_xor(s0, off, 64);
        s1 += __shfl_xor(s1, off, 64);
        s2 += __shfl_xor(s2, off, 64);
      }
      s0 *= 0.125f; s1 *= 0.125f; s2 *= 0.125f;
      float mx = fmaxf(s0, fmaxf(s1, s2));
      float e0 = __expf(s0 - mx), e1 = __expf(s1 - mx), e2 = __expf(s2 - mx);
      float inv = 1.f / (e0 + e1 + e2);
      int grow = mbase + wm * 48 + m * 16 + kg * 4 + j;
      if (l15 == 0){
        float2 a12 = {e1 * inv, e2 * inv};
        *(float2*)(acoef + (size_t)grow * 32 + hglob * 2) = a12;
      }
    }
  }
}

// ------- out = x + base + acoef @ D  (rank-32, float4 I/O, 16 rows/block) ----
// Thread = 4 consecutive cols x 16 rows; block = 16 rows x 1024 cols.
// Grid 660 rtiles * 3 cchunks = 1980. Halves D re-read traffic vs 8-row.
__global__ __launch_bounds__(256) void k_rank32v(const float* __restrict__ x,
    const float* __restrict__ acoef, const float* __restrict__ D,
    const float* __restrict__ base, float* __restrict__ out){
  __shared__ __align__(16) float as[16][32];
  const int tid = threadIdx.x;
  const int rb = blockIdx.x / 3, cc = blockIdx.x % 3;
  const int r0 = rb * 16;                    // 660*16 = 10560 exact
  const int c  = cc * 1024 + tid * 4;

  // x prefetch: 16 rows, issued before the k-loop -> overlaps D/a reads + FMA
  f32x4 xv[16];
  #pragma unroll
  for (int r = 0; r < 16; ++r)
    xv[r] = *(const f32x4*)(x + (size_t)(r0 + r) * 3072 + c);

  ((float2*)as)[tid] = ((const float2*)(acoef + (size_t)r0 * 32))[tid];
  __syncthreads();

  f32x4 accv[16];
  #pragma unroll
  for (int r = 0; r < 16; ++r) accv[r] = {0.f, 0.f, 0.f, 0.f};

  #pragma unroll
  for (int k4 = 0; k4 < 8; ++k4){
    f32x4 d0 = *(const f32x4*)(D + (size_t)(k4 * 4 + 0) * 3072 + c);
    f32x4 d1 = *(const f32x4*)(D + (size_t)(k4 * 4 + 1) * 3072 + c);
    f32x4 d2 = *(const f32x4*)(D + (size_t)(k4 * 4 + 2) * 3072 + c);
    f32x4 d3 = *(const f32x4*)(D + (size_t)(k4 * 4 + 3) * 3072 + c);
    #pragma unroll
    for (int r = 0; r < 16; ++r){
      f32x4 a4 = *(const f32x4*)(&as[r][k4 * 4]);   // one ds_read_b128
      accv[r][0] += a4[0]*d0[0] + a4[1]*d1[0] + a4[2]*d2[0] + a4[3]*d3[0];
      accv[r][1] += a4[0]*d0[1] + a4[1]*d1[1] + a4[2]*d2[1] + a4[3]*d3[1];
      accv[r][2] += a4[0]*d0[2] + a4[1]*d1[2] + a4[2]*d2[2] + a4[3]*d3[2];
      accv[r][3] += a4[0]*d0[3] + a4[1]*d1[3] + a4[2]*d2[3] + a4[3]*d3[3];
    }
  }

  f32x4 b4 = *(const f32x4*)(base + c);
  #pragma unroll
  for (int r = 0; r < 16; ++r){
    const size_t o = (size_t)(r0 + r) * 3072 + c;
    f32x4 ov;
    ov[0] = xv[r][0] + b4[0] + accv[r][0];
    ov[1] = xv[r][1] + b4[1] + accv[r][1];
    ov[2] = xv[r][2] + b4[2] + accv[r][2];
    ov[3] = xv[r][3] + b4[3] + accv[r][3];
    *(f32x4*)(out + o) = ov;
  }
}

extern "C" void kernel_launch(void* const* d_in, const int* in_sizes, int n_in,
                              void* d_out, int out_size, void* d_ws, size_t ws_size,
                              hipStream_t stream){
  const float* x    = (const float*)d_in[0];
  const float* cond = (const float*)d_in[1];
  const float* mew1 = (const float*)d_in[2];
  const float* meb1 = (const float*)d_in[3];
  const float* mew2 = (const float*)d_in[4];
  const float* meb2 = (const float*)d_in[5];
  const float* qw   = (const float*)d_in[6];
  const float* qb   = (const float*)d_in[7];
  const float* kvw  = (const float*)d_in[8];
  const float* kvb  = (const float*)d_in[9];
  const float* qnw  = (const float*)d_in[10];
  const float* knw  = (const float*)d_in[11];
  const float* ow   = (const float*)d_in[12];
  const float* ob   = (const float*)d_in[13];

  char* ws = (char*)d_ws;
  float*    emb    = (float*)(ws + 0);          // 16x512 f32
  float*    kvpart = (float*)(ws + 32768);      // 16x6144 f32
  float*    kn     = (float*)(ws + 425984);     // 3x1024 f32
  float*    vv     = (float*)(ws + 438272);     // 3x1024 f32
  ushort_t* qwt    = (ushort_t*)(ws + 450560);  // [1024][3072] bf16
  float*    U      = (float*)(ws + 6742016);    // [48][3072] f32
  float*    base   = (float*)(ws + 7331840);    // [3072] f32
  float*    Dbuf   = (float*)(ws + 7344128);    // [32][3072] f32
  float*    acoef  = (float*)(ws + 7737344);    // [10560][32] f32
  float*    h1buf  = (float*)(ws + 9089024);    // 16x512 f32

  // xb (bf16 x) lives in d_out: needed only until the Q-GEMM; k_rank32v
  // fully overwrites d_out at the end of every call.
  ushort_t* xb = (ushort_t*)d_out;

  k_pre1<<<8, 256, 0, stream>>>(cond, mew1, meb1, h1buf);
  k_pre2<<<32, 256, 0, stream>>>(h1buf, mew2, meb2, emb);
  k_kv<<<384, 256, 0, stream>>>(emb, kvw, kvpart);
  k_knorm<<<1, 256, 0, stream>>>(kvpart, kvb, knw, kn, vv);
  k_uv<<<288, 512, 0, stream>>>(vv, ow, U);
  k_ubase<<<12, 256, 0, stream>>>(U, ob, base, Dbuf);
  k_tconv<<<3072, 256, 0, stream>>>(qw, qwt, 3072, 1024);
  k_xconv<<<2048, 256, 0, stream>>>(x, xb, (TOK * CIMG) / 4);
  gemm_fused<<<440, 512, 0, stream>>>(xb, qwt, qb, kn, qnw, acoef);
  k_rank32v<<<1980, 256, 0, stream>>>(x, acoef, Dbuf, base, (float*)d_out);
}

// Round 21
// 258.780 us; speedup vs baseline: 1.3632x; 1.0218x over previous
//
#include <hip/hip_runtime.h>

#define TOK  10560
#define CIMG 3072
#define KHD  1024

typedef unsigned short ushort_t;
typedef unsigned int u32;
using bf16x8 = __attribute__((ext_vector_type(8))) __bf16;
using f32x4  = __attribute__((ext_vector_type(4))) float;

#define GLD_LDS16(gp, lp) __builtin_amdgcn_global_load_lds( \
    (const __attribute__((address_space(1))) u32*)(gp), \
    (__attribute__((address_space(3))) u32*)(lp), 16, 0, 0)

static __device__ __forceinline__ unsigned short f2bf(float f){
  union { float f; unsigned u; } x; x.f = f;
  unsigned r = x.u + 0x7fffu + ((x.u >> 16) & 1u);
  return (unsigned short)(r >> 16);
}
static __device__ __forceinline__ float wave_sum(float v){
  #pragma unroll
  for (int off = 32; off > 0; off >>= 1) v += __shfl_xor(v, off, 64);
  return v;
}

// ---------------- conditioning MLP layer 1: h1 = silu(cp@w1+b1) --------------
__global__ __launch_bounds__(256) void k_pre1(const float* __restrict__ cond,
    const float* __restrict__ w1, const float* __restrict__ b1,
    float* __restrict__ h1){
  __shared__ float cs[16][16];
  int t = threadIdx.x;
  if (t < 256) cs[t >> 4][t & 15] = cond[(64 + (t >> 4)) * 16 + (t & 15)];
  __syncthreads();
  #pragma unroll
  for (int i = 0; i < 4; ++i){
    int idx = blockIdx.x * 256 + t + i * 2048;
    int r = idx >> 9, c = idx & 511;
    float s = b1[c];
    #pragma unroll
    for (int j = 0; j < 16; ++j) s += cs[r][j] * w1[j * 512 + c];
    h1[idx] = s / (1.f + __expf(-s));   // silu
  }
}

// ---------------- conditioning MLP layer 2: emb = h1@w2 + b2 -----------------
__global__ __launch_bounds__(256) void k_pre2(const float* __restrict__ h1,
    const float* __restrict__ w2, const float* __restrict__ b2,
    float* __restrict__ emb){
  int idx = blockIdx.x * 256 + threadIdx.x;
  int r = idx >> 9, c = idx & 511;
  const float* hp = h1 + r * 512;
  const float* wp = w2 + c;
  float acc = b2[c];
  #pragma unroll 8
  for (int j = 0; j < 512; ++j) acc += hp[j] * wp[(size_t)j * 512];
  emb[idx] = acc;
}

// ---------------- kv = mf @ kv_w, split-K partials (deterministic) ----------
__global__ __launch_bounds__(256) void k_kv(const float* __restrict__ emb,
                                            const float* __restrict__ kvw,
                                            float* __restrict__ part){
  int bl = blockIdx.x;                 // 3 l * 8 ntile * 16 kchunk = 384
  int l = bl / 128, rem = bl % 128, nt = rem / 16, kc = rem % 16;
  int n = nt * 256 + threadIdx.x;
  const float* e = emb + 2048 * l + kc * 256;   // mf[l][r] = emb[2048l + r]
  const float* w = kvw + (size_t)(kc * 256) * 2048 + n;
  float acc = 0.f;
  for (int r = 0; r < 256; ++r) acc += e[r] * w[(size_t)r * 2048];
  part[kc * 6144 + l * 2048 + n] = acc;
}

// ---------------- reduce partials, bias, k-RMSNorm ---------------------------
__global__ void k_knorm(const float* __restrict__ part, const float* __restrict__ kvb,
                        const float* __restrict__ knw, float* __restrict__ kn,
                        float* __restrict__ vv){
  int wid = threadIdx.x >> 6, lane = threadIdx.x & 63;
  for (int i = 0; i < 12; ++i){
    int g = wid * 12 + i;               // 0..47 = (l,h)
    int l = g >> 4, h = g & 15;
    int ik = l * 2048 + h * 64 + lane;
    float kk = kvb[h * 64 + lane];
    float v  = kvb[1024 + h * 64 + lane];
    for (int p = 0; p < 16; ++p){ kk += part[p * 6144 + ik]; v += part[p * 6144 + ik + 1024]; }
    float ss = wave_sum(kk * kk);
    kn[l * 1024 + h * 64 + lane] = kk * rsqrtf(ss * (1.f/64.f) + 1e-6f) * knw[lane];
    vv[l * 1024 + h * 64 + lane] = v;
  }
}

// ------- U[h*3+l][c] = sum_d v[l,h,d] * out_w[h*64+d][c]  (48 x 3072, f32) ---
__global__ __launch_bounds__(512) void k_uv(const float* __restrict__ vv,
    const float* __restrict__ ow, float* __restrict__ U){
  int b = blockIdx.x;             // 48 i * 6 cchunk = 288
  int i = b / 6, cc = b % 6;
  int h = i / 3, l = i % 3;
  int c = cc * 512 + threadIdx.x;
  const float* vp = vv + l * 1024 + h * 64;
  const float* wp = ow + (size_t)(h * 64) * 3072 + c;
  float acc = 0.f;
  #pragma unroll
  for (int d = 0; d < 64; ++d) acc += vp[d] * wp[(size_t)d * 3072];
  U[(size_t)i * 3072 + c] = acc;
}

// ------- base[c] = ob[c] + sum_h U[h*3][c];  D[h*2+l'][c] = U[h*3+1+l']-U[h*3]
__global__ __launch_bounds__(256) void k_ubase(const float* __restrict__ U,
    const float* __restrict__ ob, float* __restrict__ base, float* __restrict__ D){
  int c = blockIdx.x * 256 + threadIdx.x;   // 12 blocks
  float b = ob[c];
  #pragma unroll
  for (int h = 0; h < 16; ++h){
    float u0 = U[(size_t)(h * 3 + 0) * 3072 + c];
    float u1 = U[(size_t)(h * 3 + 1) * 3072 + c];
    float u2 = U[(size_t)(h * 3 + 2) * 3072 + c];
    b += u0;
    D[(size_t)(h * 2 + 0) * 3072 + c] = u1 - u0;
    D[(size_t)(h * 2 + 1) * 3072 + c] = u2 - u0;
  }
  base[c] = b;
}

// ---------------- transpose + f32->bf16 weight convert: dst[C][R] ------------
__global__ __launch_bounds__(256) void k_tconv(const float* __restrict__ src,
                                               ushort_t* __restrict__ dst,
                                               int R, int C){
  __shared__ float tile[32][33];
  int nTr = R >> 5;
  int tr = blockIdx.x % nTr, tc = blockIdx.x / nTr;
  int r0 = tr * 32, c0 = tc * 32, t = threadIdx.x;
  #pragma unroll
  for (int i = 0; i < 4; ++i){
    int idx = t + i * 256; int r = idx >> 5, c = idx & 31;
    tile[r][c] = src[(size_t)(r0 + r) * C + c0 + c];
  }
  __syncthreads();
  #pragma unroll
  for (int i = 0; i < 4; ++i){
    int idx = t + i * 256; int rr = idx >> 5, cc = idx & 31;
    dst[(size_t)(c0 + rr) * R + r0 + cc] = f2bf(tile[cc][rr]);
  }
}

// ---------------- x f32 -> bf16 streaming convert ----------------------------
__global__ __launch_bounds__(256) void k_xconv(const float* __restrict__ x,
                                               ushort_t* __restrict__ xb, int n4){
  for (int i = blockIdx.x * 256 + threadIdx.x; i < n4; i += gridDim.x * 256){
    float4 v = ((const float4*)x)[i];
    ushort4 o;
    o.x = f2bf(v.x); o.y = f2bf(v.y); o.z = f2bf(v.z); o.w = f2bf(v.w);
    ((ushort4*)xb)[i] = o;
  }
}

// ======== 192x128 bf16 MFMA Q-GEMM, BK=32, 4-deep LDS ring, fused attn =======
// (round-18 version, byte-identical — verified 95us, total-best 260us)
__global__ __launch_bounds__(512, 4) void gemm_fused(
    const ushort_t* __restrict__ A, const ushort_t* __restrict__ Bt,
    const float* __restrict__ bias, const float* __restrict__ kn,
    const float* __restrict__ qnw, float* __restrict__ acoef){
  __shared__ __align__(16) unsigned char lds[81920];
  const int tid = threadIdx.x;
  const int lane = tid & 63, wid = tid >> 6;
  const int wm = wid >> 1, wn = wid & 1;     // 4 x 2 waves -> per-wave 48x64
  const int l15 = lane & 15, kg = lane >> 4;

  // XCD swizzle: 440 = 8 * 55 -> bijective
  int bid = blockIdx.x;
  bid = (bid & 7) * 55 + (bid >> 3);
  const int mt = bid >> 3, nt = bid & 7;
  const int mbase = mt * 192, nbase = nt << 7;

  // staging pointers (per thread): src chunk swizzled, dst linear 1KB slots
  const int skb = ((lane & 3) ^ ((lane >> 4) & 3)) * 8;   // elem offset
  const int lrow = lane >> 2;                             // 0..15 within slot
  const ushort_t *g0, *g1, *g2, *g3;
  int d0, d1, d2, d3;
  if (wid < 6){
    int r0 = (wid * 2 + 0) * 16 + lrow;
    int r1 = (wid * 2 + 1) * 16 + lrow;
    g0 = A + (size_t)(mbase + r0) * CIMG + skb;
    g1 = A + (size_t)(mbase + r1) * CIMG + skb;
    g2 = g0; g3 = g0;
    d0 = (wid * 2 + 0) * 1024;
    d1 = (wid * 2 + 1) * 1024;
    d2 = d0; d3 = d0;
  } else {
    int v = wid - 6;
    int r0 = (v * 4 + 0) * 16 + lrow, r1 = (v * 4 + 1) * 16 + lrow;
    int r2 = (v * 4 + 2) * 16 + lrow, r3 = (v * 4 + 3) * 16 + lrow;
    g0 = Bt + (size_t)(nbase + r0) * CIMG + skb;
    g1 = Bt + (size_t)(nbase + r1) * CIMG + skb;
    g2 = Bt + (size_t)(nbase + r2) * CIMG + skb;
    g3 = Bt + (size_t)(nbase + r3) * CIMG + skb;
    d0 = 12288 + (v * 4 + 0) * 1024;
    d1 = 12288 + (v * 4 + 1) * 1024;
    d2 = 12288 + (v * 4 + 2) * 1024;
    d3 = 12288 + (v * 4 + 3) * 1024;
  }

  auto stage = [&](int t){
    const int gk = t * 32;
    const int bo = (t & 3) * 20480;
    if (wid < 6){
      GLD_LDS16(g0 + gk, lds + bo + d0);
      GLD_LDS16(g1 + gk, lds + bo + d1);
    } else {
      GLD_LDS16(g0 + gk, lds + bo + d0);
      GLD_LDS16(g1 + gk, lds + bo + d1);
      GLD_LDS16(g2 + gk, lds + bo + d2);
      GLD_LDS16(g3 + gk, lds + bo + d3);
    }
  };

  // fragment read bases
  const int swz = (kg ^ ((l15 >> 2) & 3)) * 16;
  const unsigned aBase = (unsigned)((wm * 48 + l15) * 64 + swz);
  const unsigned bBase = (unsigned)(12288 + (wn * 64 + l15) * 64 + swz);

  f32x4 acc[3][4];
  #pragma unroll
  for (int m = 0; m < 3; ++m)
    #pragma unroll
    for (int n = 0; n < 4; ++n) acc[m][n] = {0.f, 0.f, 0.f, 0.f};

  bf16x8 afr[3], bfr[4];

  const int T = CIMG / 32;   // 96

  stage(0); stage(1); stage(2);

  for (int t = 0; t < T; ++t){
    if (t < T - 2){
      if (wid < 6) asm volatile("s_waitcnt vmcnt(4)" ::: "memory");
      else         asm volatile("s_waitcnt vmcnt(8)" ::: "memory");
    } else if (t == T - 2){
      if (wid < 6) asm volatile("s_waitcnt vmcnt(2)" ::: "memory");
      else         asm volatile("s_waitcnt vmcnt(4)" ::: "memory");
    } else {
      asm volatile("s_waitcnt vmcnt(0)" ::: "memory");
    }
    __builtin_amdgcn_s_barrier();
    asm volatile("" ::: "memory");
    if (t + 3 < T) stage(t + 3);
    const unsigned char* base = lds + (t & 3) * 20480;
    #pragma unroll
    for (int n = 0; n < 4; ++n)
      bfr[n] = *(const bf16x8*)(base + bBase + n * 1024);
    #pragma unroll
    for (int m = 0; m < 3; ++m)
      afr[m] = *(const bf16x8*)(base + aBase + m * 1024);
    __builtin_amdgcn_s_setprio(1);
    #pragma unroll
    for (int m = 0; m < 3; ++m)
      #pragma unroll
      for (int n = 0; n < 4; ++n)
        acc[m][n] = __builtin_amdgcn_mfma_f32_16x16x32_bf16(afr[m], bfr[n], acc[m][n], 0, 0, 0);
    __builtin_amdgcn_s_setprio(0);
  }

  // -------- fused attention epilogue (registers + 16-lane shfl only) --------
  const int hglob = nt * 2 + wn;            // global head, 0..15
  float qnwv[4], qbv[4], knv0[4], knv1[4], knv2[4];
  #pragma unroll
  for (int n = 0; n < 4; ++n){
    int d = n * 16 + l15;
    qnwv[n] = qnw[d];
    qbv[n]  = bias[nbase + wn * 64 + d];
    knv0[n] = kn[hglob * 64 + d];
    knv1[n] = kn[1024 + hglob * 64 + d];
    knv2[n] = kn[2048 + hglob * 64 + d];
  }
  #pragma unroll
  for (int m = 0; m < 3; ++m){
    #pragma unroll
    for (int j = 0; j < 4; ++j){
      float q[4], ssq = 0.f;
      #pragma unroll
      for (int n = 0; n < 4; ++n){ q[n] = acc[m][n][j] + qbv[n]; ssq += q[n] * q[n]; }
      #pragma unroll
      for (int off = 1; off < 16; off <<= 1) ssq += __shfl_xor(ssq, off, 64);
      float rs = rsqrtf(ssq * (1.f/64.f) + 1e-6f);
      float s0 = 0.f, s1 = 0.f, s2 = 0.f;
      #pragma unroll
      for (int n = 0; n < 4; ++n){
        float qn = q[n] * rs * qnwv[n];
        s0 += qn * knv0[n]; s1 += qn * knv1[n]; s2 += qn * knv2[n];
      }
      #pragma unroll
      for (int off = 1; off < 16; off <<= 1){
        s0 += __shfl_xor(s0, off, 64);
        s1 += __shfl_xor(s1, off, 64);
        s2 += __shfl_xor(s2, off, 64);
      }
      s0 *= 0.125f; s1 *= 0.125f; s2 *= 0.125f;
      float mx = fmaxf(s0, fmaxf(s1, s2));
      float e0 = __expf(s0 - mx), e1 = __expf(s1 - mx), e2 = __expf(s2 - mx);
      float inv = 1.f / (e0 + e1 + e2);
      int grow = mbase + wm * 48 + m * 16 + kg * 4 + j;
      if (l15 == 0){
        float2 a12 = {e1 * inv, e2 * inv};
        *(float2*)(acoef + (size_t)grow * 32 + hglob * 2) = a12;
      }
    }
  }
}

// ------- out = x + base + acoef @ D  (rank-32, float4 I/O, b128 LDS reads) ---
// (round-18 version, byte-identical — 8 rows/block)
__global__ __launch_bounds__(256) void k_rank32v(const float* __restrict__ x,
    const float* __restrict__ acoef, const float* __restrict__ D,
    const float* __restrict__ base, float* __restrict__ out){
  __shared__ __align__(16) float as[8][32];
  const int tid = threadIdx.x;
  const int rb = blockIdx.x / 3, cc = blockIdx.x % 3;
  const int r0 = rb * 8;                     // 1320*8 = 10560 exact
  const int c  = cc * 1024 + tid * 4;

  // x prefetch: 8 rows, issued before the k-loop -> overlaps D/a reads + FMA
  f32x4 xv[8];
  #pragma unroll
  for (int r = 0; r < 8; ++r)
    xv[r] = *(const f32x4*)(x + (size_t)(r0 + r) * 3072 + c);

  if (tid < 256) ((float*)as)[tid] = acoef[(size_t)r0 * 32 + tid];
  __syncthreads();

  f32x4 accv[8];
  #pragma unroll
  for (int r = 0; r < 8; ++r) accv[r] = {0.f, 0.f, 0.f, 0.f};

  #pragma unroll
  for (int k4 = 0; k4 < 8; ++k4){
    f32x4 d0 = *(const f32x4*)(D + (size_t)(k4 * 4 + 0) * 3072 + c);
    f32x4 d1 = *(const f32x4*)(D + (size_t)(k4 * 4 + 1) * 3072 + c);
    f32x4 d2 = *(const f32x4*)(D + (size_t)(k4 * 4 + 2) * 3072 + c);
    f32x4 d3 = *(const f32x4*)(D + (size_t)(k4 * 4 + 3) * 3072 + c);
    #pragma unroll
    for (int r = 0; r < 8; ++r){
      f32x4 a4 = *(const f32x4*)(&as[r][k4 * 4]);   // one ds_read_b128
      accv[r][0] += a4[0]*d0[0] + a4[1]*d1[0] + a4[2]*d2[0] + a4[3]*d3[0];
      accv[r][1] += a4[0]*d0[1] + a4[1]*d1[1] + a4[2]*d2[1] + a4[3]*d3[1];
      accv[r][2] += a4[0]*d0[2] + a4[1]*d1[2] + a4[2]*d2[2] + a4[3]*d3[2];
      accv[r][3] += a4[0]*d0[3] + a4[1]*d1[3] + a4[2]*d2[3] + a4[3]*d3[3];
    }
  }

  f32x4 b4 = *(const f32x4*)(base + c);
  #pragma unroll
  for (int r = 0; r < 8; ++r){
    const size_t o = (size_t)(r0 + r) * 3072 + c;
    f32x4 ov;
    ov[0] = xv[r][0] + b4[0] + accv[r][0];
    ov[1] = xv[r][1] + b4[1] + accv[r][1];
    ov[2] = xv[r][2] + b4[2] + accv[r][2];
    ov[3] = xv[r][3] + b4[3] + accv[r][3];
    *(f32x4*)(out + o) = ov;
  }
}

extern "C" void kernel_launch(void* const* d_in, const int* in_sizes, int n_in,
                              void* d_out, int out_size, void* d_ws, size_t ws_size,
                              hipStream_t stream){
  const float* x    = (const float*)d_in[0];
  const float* cond = (const float*)d_in[1];
  const float* mew1 = (const float*)d_in[2];
  const float* meb1 = (const float*)d_in[3];
  const float* mew2 = (const float*)d_in[4];
  const float* meb2 = (const float*)d_in[5];
  const float* qw   = (const float*)d_in[6];
  const float* qb   = (const float*)d_in[7];
  const float* kvw  = (const float*)d_in[8];
  const float* kvb  = (const float*)d_in[9];
  const float* qnw  = (const float*)d_in[10];
  const float* knw  = (const float*)d_in[11];
  const float* ow   = (const float*)d_in[12];
  const float* ob   = (const float*)d_in[13];

  char* ws = (char*)d_ws;
  float*    emb    = (float*)(ws + 0);          // 16x512 f32
  float*    kvpart = (float*)(ws + 32768);      // 16x6144 f32
  float*    kn     = (float*)(ws + 425984);     // 3x1024 f32
  float*    vv     = (float*)(ws + 438272);     // 3x1024 f32
  ushort_t* qwt    = (ushort_t*)(ws + 450560);  // [1024][3072] bf16
  float*    U      = (float*)(ws + 6742016);    // [48][3072] f32
  float*    base   = (float*)(ws + 7331840);    // [3072] f32
  float*    Dbuf   = (float*)(ws + 7344128);    // [32][3072] f32
  float*    acoef  = (float*)(ws + 7737344);    // [10560][32] f32
  float*    h1buf  = (float*)(ws + 9089024);    // 16x512 f32

  // xb (bf16 x) lives in d_out: needed only until the Q-GEMM; k_rank32v
  // fully overwrites d_out at the end of every call.
  ushort_t* xb = (ushort_t*)d_out;

  k_pre1<<<8, 256, 0, stream>>>(cond, mew1, meb1, h1buf);
  k_pre2<<<32, 256, 0, stream>>>(h1buf, mew2, meb2, emb);
  k_kv<<<384, 256, 0, stream>>>(emb, kvw, kvpart);
  k_knorm<<<1, 256, 0, stream>>>(kvpart, kvb, knw, kn, vv);
  k_uv<<<288, 512, 0, stream>>>(vv, ow, U);
  k_ubase<<<12, 256, 0, stream>>>(U, ob, base, Dbuf);
  k_tconv<<<3072, 256, 0, stream>>>(qw, qwt, 3072, 1024);
  k_xconv<<<2048, 256, 0, stream>>>(x, xb, (TOK * CIMG) / 4);
  gemm_fused<<<440, 512, 0, stream>>>(xb, qwt, qb, kn, qnw, acoef);
  k_rank32v<<<1320 * 3, 256, 0, stream>>>(x, acoef, Dbuf, base, (float*)d_out);
}